// Round 5
// baseline (293.536 us; speedup 1.0000x reference)
//
#include <hip/hip_runtime.h>
#include <hip/hip_bf16.h>
#include <stdint.h>

#define NB 16
#define NS 1024
#define ND 512
#define NO 512
#define NROW (NB*NS)   // 16384
#define SIM_BAND 8.5e-3f
#define LIST_CAP 524288

typedef float f32x4 __attribute__((ext_vector_type(4)));
typedef __bf16 bf16x8 __attribute__((ext_vector_type(8)));

#define GLOAD_LDS16(g, l) __builtin_amdgcn_global_load_lds( \
    (const __attribute__((address_space(1))) void*)(g), \
    (__attribute__((address_space(3))) void*)(l), 16, 0, 0)

__device__ inline unsigned short f2bs(float f) {
  union { __hip_bfloat16 h; unsigned short u; } c;
  c.h = __float2bfloat16(f);
  return c.u;
}

// ---------------- K1: Wt[o][d] = bf16(W[d][o]) ----------------
__global__ __launch_bounds__(1024) void k_prep_w(const float* __restrict__ W,
                                                 __hip_bfloat16* __restrict__ Wt) {
  __shared__ float tile[32][33];
  int o0 = blockIdx.x*32, d0 = blockIdx.y*32;
  int tx = threadIdx.x, ty = threadIdx.y;
  tile[ty][tx] = W[(size_t)(d0+ty)*NO + o0+tx];
  __syncthreads();
  Wt[(size_t)(o0+ty)*ND + d0+tx] = __float2bfloat16(tile[tx][ty]);
}

// ---------------- K2: watt_s[d] = sum_o W[d][o]*att_src[o]; same for dst ----------------
__global__ __launch_bounds__(256) void k_prep_watt(const float* __restrict__ W,
                                                   const float* __restrict__ att_src,
                                                   const float* __restrict__ att_dst,
                                                   float* __restrict__ watt_s,
                                                   float* __restrict__ watt_d) {
  __shared__ float as_[512], ad_[512];
  int tid = threadIdx.x;
  as_[tid] = att_src[tid]; as_[tid+256] = att_src[tid+256];
  ad_[tid] = att_dst[tid]; ad_[tid+256] = att_dst[tid+256];
  __syncthreads();
  int d = blockIdx.x*256 + tid;
  const float* wr = W + (size_t)d*NO;
  float s = 0.f, dd = 0.f;
  for (int o = 0; o < NO; o += 4) {
    float4 w = *(const float4*)&wr[o];
    s  = fmaf(w.x, as_[o],   fmaf(w.y, as_[o+1], fmaf(w.z, as_[o+2], fmaf(w.w, as_[o+3], s))));
    dd = fmaf(w.x, ad_[o],   fmaf(w.y, ad_[o+1], fmaf(w.z, ad_[o+2], fmaf(w.w, ad_[o+3], dd))));
  }
  watt_s[d] = s;
  watt_d[d] = dd;
}

// ---------------- K3: rnorm, a_src, a_dst, xb (row-major bf16), yhi (fragment-order bf16) ----
// yhi layout: elem off ((b*8+tblk)*8 + k0c)*8192 + id*8, id = kb*512 + m*64 + g*16 + r
__global__ __launch_bounds__(256) void k_prep_y(const float* __restrict__ x,
                                                __hip_bfloat16* __restrict__ xb,
                                                __hip_bfloat16* __restrict__ yhi,
                                                float* __restrict__ rnorm,
                                                float* __restrict__ a_src,
                                                float* __restrict__ a_dst,
                                                const float* __restrict__ watt_s,
                                                const float* __restrict__ watt_d,
                                                int* __restrict__ counter) {
  __shared__ float ws_[512], wd_[512];
  int tid = threadIdx.x, blk = blockIdx.x;
  if (blk == 0 && tid == 0) *counter = 0;
  ws_[tid] = watt_s[tid]; ws_[tid+256] = watt_s[tid+256];
  wd_[tid] = watt_d[tid]; wd_[tid+256] = watt_d[tid+256];
  __syncthreads();
  int r = tid>>2, q = tid&3;            // 64 rows/block, 4 lanes/row (128 cols each)
  int grow = blk*64 + r;                // grid 256
  const float* xr = x + (size_t)grow*ND + q*128;
  // pass 1: ssq + logits dots + xb store
  float ssq = 0.f, as = 0.f, ad = 0.f;
  #pragma unroll
  for (int c8 = 0; c8 < 16; ++c8) {
    float4 v0 = *(const float4*)&xr[c8*8];
    float4 v1 = *(const float4*)&xr[c8*8+4];
    float vv[8] = {v0.x,v0.y,v0.z,v0.w,v1.x,v1.y,v1.z,v1.w};
    union { unsigned short us[8]; uint4 u; } pk;
    #pragma unroll
    for (int j = 0; j < 8; ++j) {
      int c = q*128 + c8*8 + j;
      ssq = fmaf(vv[j], vv[j], ssq);
      as  = fmaf(vv[j], ws_[c], as);
      ad  = fmaf(vv[j], wd_[c], ad);
      pk.us[j] = f2bs(vv[j]);
    }
    *(uint4*)&xb[(size_t)grow*ND + q*128 + c8*8] = pk.u;
  }
  ssq += __shfl_xor(ssq, 1, 64); ssq += __shfl_xor(ssq, 2, 64);
  as  += __shfl_xor(as, 1, 64);  as  += __shfl_xor(as, 2, 64);
  ad  += __shfl_xor(ad, 1, 64);  ad  += __shfl_xor(ad, 2, 64);
  float rn = 1.0f / fmaxf(sqrtf(ssq), 1e-12f);
  if (q == 0) { rnorm[grow] = rn; a_src[grow] = as; a_dst[grow] = ad; }
  // pass 2: yhi (normalized, RTN bf16) in fragment order
  int trow = grow & (NS-1), b = grow >> 10;
  int m = (trow>>4)&7, rr = trow&15;
  size_t tilebase = ((size_t)(b*8 + (trow>>7)))*65536;
  #pragma unroll
  for (int c8 = 0; c8 < 16; ++c8) {
    int col = q*128 + c8*8;
    int k0c = col>>6, cc = col&63, kb = cc>>5, g = (cc>>3)&3;
    int id = kb*512 + m*64 + g*16 + rr;
    float4 v0 = *(const float4*)&xr[c8*8];
    float4 v1 = *(const float4*)&xr[c8*8+4];
    float vv[8] = {v0.x,v0.y,v0.z,v0.w,v1.x,v1.y,v1.z,v1.w};
    union { unsigned short us[8]; uint4 u; } pk;
    #pragma unroll
    for (int j = 0; j < 8; ++j) pk.us[j] = f2bs(vv[j]*rn);
    *(uint4*)&yhi[tilebase + (size_t)k0c*8192 + id*8] = pk.u;
  }
}

// ---------------- K4: hi-only bf16 MFMA sim -> bit mask + borderline list ----------------
__global__ __launch_bounds__(256) void k_sim_mfma(const __hip_bfloat16* __restrict__ yhi,
                                                  uint16_t* __restrict__ Mbits,
                                                  unsigned int* __restrict__ list,
                                                  int* __restrict__ counter) {
  int bid = blockIdx.x;
  int swz = (bid & 7)*72 + (bid >> 3);      // bijective: 576 = 8*72
  int b = swz / 36, p = swz - b*36;
  int ti = 0;
  while ((ti+1)*(ti+2)/2 <= p) ++ti;
  int tj = p - ti*(ti+1)/2;                 // tj <= ti
  __shared__ __hip_bfloat16 Ah[8192], Bh2[8192];
  int tid = threadIdx.x, wid = tid>>6, lane = tid&63;
  int wm = (wid>>1)*64, wn = (wid&1)*64;
  bool diag = (ti == tj);
  const __hip_bfloat16* Bh = diag ? Ah : Bh2;
  f32x4 acc[4][4] = {};
  for (int k0c = 0; k0c < 8; ++k0c) {
    __syncthreads();
    size_t abase = ((size_t)((b*8+ti)*8 + k0c))*8192 + wid*2048 + lane*8;
    size_t bbase = ((size_t)((b*8+tj)*8 + k0c))*8192 + wid*2048 + lane*8;
    int lb = wid*2048;
    #pragma unroll
    for (int i = 0; i < 4; ++i) GLOAD_LDS16(yhi + abase + i*512, &Ah[lb + i*512]);
    if (!diag) {
      #pragma unroll
      for (int i = 0; i < 4; ++i) GLOAD_LDS16(yhi + bbase + i*512, &Bh2[lb + i*512]);
    }
    __syncthreads();
    #pragma unroll
    for (int kb = 0; kb < 2; ++kb) {
      bf16x8 ah[4], bh[4];
      #pragma unroll
      for (int qq = 0; qq < 4; ++qq) {
        ah[qq] = *(const bf16x8*)&Ah[((kb*8 + (wm>>4) + qq)*64 + lane)*8];
        bh[qq] = *(const bf16x8*)&Bh[((kb*8 + (wn>>4) + qq)*64 + lane)*8];
      }
      #pragma unroll
      for (int mi = 0; mi < 4; ++mi)
        #pragma unroll
        for (int ni = 0; ni < 4; ++ni)
          acc[mi][ni] = __builtin_amdgcn_mfma_f32_16x16x32_bf16(ah[mi], bh[ni], acc[mi][ni], 0,0,0);
    }
  }
  int hi = lane>>4, colL = lane&15;
  #pragma unroll
  for (int mi = 0; mi < 4; ++mi) {
    #pragma unroll
    for (int r2 = 0; r2 < 4; ++r2) {
      int t_g = ti*128 + wm + mi*16 + hi*4 + r2;
      int git = b*NS + t_g;
      #pragma unroll
      for (int ni = 0; ni < 4; ++ni) {
        int s_g = tj*128 + wn + ni*16 + colL;
        float sim = acc[mi][ni][r2];
        bool bit = (s_g == t_g) || (s_g < t_g && sim > 0.9f);
        if (s_g < t_g && fabsf(sim - 0.9f) <= SIM_BAND) {
          int idx = atomicAdd(counter, 1);
          if (idx < LIST_CAP) list[idx] = ((unsigned)b<<20) | ((unsigned)t_g<<10) | (unsigned)s_g;
        }
        unsigned long long bal = __ballot(bit);
        if (colL == 0) {
          uint16_t slice = (uint16_t)((bal >> (hi*16)) & 0xFFFFull);
          Mbits[(size_t)git*64 + ((tj*128 + wn + ni*16)>>4)] = slice;
        }
      }
    }
  }
}

// ---------------- K5: exact f32 recheck of borderline pairs -> fix bits ----------------
__global__ __launch_bounds__(256) void k_recheck(const float* __restrict__ x,
                                                 const float* __restrict__ rnorm,
                                                 uint32_t* __restrict__ Mw,
                                                 const unsigned int* __restrict__ list,
                                                 const int* __restrict__ counter) {
  int n = *counter;
  if (n > LIST_CAP) n = LIST_CAP;
  int gid = blockIdx.x*256 + threadIdx.x;
  for (int i = gid; i < n; i += 256*256) {
    unsigned v = list[i];
    int b = v>>20, t = (v>>10)&1023, s = v&1023;
    const float* xt = x + ((size_t)(b*NS + t))*ND;
    const float* xs = x + ((size_t)(b*NS + s))*ND;
    float4 a4 = {0.f,0.f,0.f,0.f};
    for (int k = 0; k < ND; k += 4) {
      float4 av = *(const float4*)&xt[k];
      float4 bv = *(const float4*)&xs[k];
      a4.x = fmaf(av.x,bv.x,a4.x); a4.y = fmaf(av.y,bv.y,a4.y);
      a4.z = fmaf(av.z,bv.z,a4.z); a4.w = fmaf(av.w,bv.w,a4.w);
    }
    float dot = (a4.x+a4.y)+(a4.z+a4.w);
    float sim = dot * rnorm[b*NS+t] * rnorm[b*NS+s];
    int git = b*NS + t;
    uint32_t bmask = 1u << (s&31);
    if (sim > 0.9f) atomicOr (&Mw[(size_t)git*32 + (s>>5)], bmask);
    else            atomicAnd(&Mw[(size_t)git*32 + (s>>5)], ~bmask);
  }
}

// ---------------- K6: ht[o][i] via MFMA, fragment-gather DMA staging ----------------
__global__ __launch_bounds__(256) void k_gemm_ht(const __hip_bfloat16* __restrict__ Wt,
                                                 const __hip_bfloat16* __restrict__ xb,
                                                 __hip_bfloat16* __restrict__ ht) {
  __shared__ __hip_bfloat16 Ah[8192], Bh[8192];
  int m0 = blockIdx.y*128, n0 = blockIdx.x*128;
  int tid = threadIdx.x, wid = tid>>6, lane = tid&63;
  int wm = (wid>>1)*64, wn = (wid&1)*64;
  f32x4 acc[4][4] = {};
  for (int k0 = 0; k0 < ND; k0 += 64) {
    __syncthreads();
    #pragma unroll
    for (int i = 0; i < 4; ++i) {
      int id = wid*256 + i*64 + lane;
      int kb = id>>9, m = (id>>6)&7, g = (id>>4)&3, rr = id&15;
      int row = m*16 + rr, col = k0 + kb*32 + g*8;
      GLOAD_LDS16(&Wt[(size_t)(m0+row)*ND + col], &Ah[(wid*256 + i*64)*8]);
      GLOAD_LDS16(&xb[(size_t)(n0+row)*ND + col], &Bh[(wid*256 + i*64)*8]);
    }
    __syncthreads();
    #pragma unroll
    for (int kb = 0; kb < 2; ++kb) {
      bf16x8 af[4], bf[4];
      #pragma unroll
      for (int qq = 0; qq < 4; ++qq) {
        af[qq] = *(const bf16x8*)&Ah[((kb*8 + (wm>>4) + qq)*64 + lane)*8];
        bf[qq] = *(const bf16x8*)&Bh[((kb*8 + (wn>>4) + qq)*64 + lane)*8];
      }
      #pragma unroll
      for (int mi = 0; mi < 4; ++mi)
        #pragma unroll
        for (int ni = 0; ni < 4; ++ni)
          acc[mi][ni] = __builtin_amdgcn_mfma_f32_16x16x32_bf16(af[mi], bf[ni], acc[mi][ni], 0,0,0);
    }
  }
  int rbase = (lane>>4)*4, col = lane&15;
  #pragma unroll
  for (int mi = 0; mi < 4; ++mi)
    #pragma unroll
    for (int ni = 0; ni < 4; ++ni) {
      int gm = m0 + wm + mi*16 + rbase;
      int gn = n0 + wn + ni*16 + col;
      #pragma unroll
      for (int r2 = 0; r2 < 4; ++r2)
        ht[(size_t)(gm+r2)*NROW + gn] = __float2bfloat16(acc[mi][ni][r2]);
    }
}

// ---------------- K7: masked softmax from bit mask -> P (bf16), wave per row ----------------
__global__ __launch_bounds__(256) void k_softmax(const uint32_t* __restrict__ Mw,
                                                 const float* __restrict__ a_src,
                                                 const float* __restrict__ a_dst,
                                                 __hip_bfloat16* __restrict__ P) {
  int wid = threadIdx.x>>6, lane = threadIdx.x&63;
  int rowid = blockIdx.x*4 + wid;
  int t = rowid & (NS-1), b = rowid >> 10;
  int n = t + 1;
  const float* as = a_src + b*NS;
  float adv = a_dst[rowid];
  uint32_t w = Mw[(size_t)rowid*32 + (lane>>1)];
  uint32_t bits16 = (lane&1) ? (w>>16) : (w & 0xFFFFu);
  int s0 = lane*16;
  float4 a0 = *(const float4*)&as[s0];
  float4 a1 = *(const float4*)&as[s0+4];
  float4 a2 = *(const float4*)&as[s0+8];
  float4 a3 = *(const float4*)&as[s0+12];
  float va[16] = {a0.x,a0.y,a0.z,a0.w, a1.x,a1.y,a1.z,a1.w,
                  a2.x,a2.y,a2.z,a2.w, a3.x,a3.y,a3.z,a3.w};
  float p[16];
  float lm = -INFINITY;
  #pragma unroll
  for (int k = 0; k < 16; ++k) {
    int s = s0 + k;
    bool on = (s < n) && ((bits16>>k)&1);
    float vv = adv + va[k];
    float v = (vv > 0.f) ? vv : 0.2f*vv;
    p[k] = on ? v : -INFINITY;
    lm = fmaxf(lm, p[k]);
  }
  #pragma unroll
  for (int off = 32; off > 0; off >>= 1) lm = fmaxf(lm, __shfl_xor(lm, off, 64));
  float ls = 0.f;
  #pragma unroll
  for (int k = 0; k < 16; ++k) { p[k] = __expf(p[k] - lm); ls += p[k]; }
  #pragma unroll
  for (int off = 32; off > 0; off >>= 1) ls += __shfl_xor(ls, off, 64);
  float inv = 1.0f / ls;
  int end = ((t >> 7) + 1) << 7;
  if (s0 < end) {
    __hip_bfloat16* Prow = P + (size_t)rowid*NS;
    union { unsigned short us[8]; uint4 u; } w0, w1;
    #pragma unroll
    for (int k = 0; k < 8; ++k)  w0.us[k] = f2bs(p[k]*inv);
    #pragma unroll
    for (int k = 0; k < 8; ++k)  w1.us[k] = f2bs(p[k+8]*inv);
    *(uint4*)&Prow[s0]   = w0.u;
    *(uint4*)&Prow[s0+8] = w1.u;
  }
}

// ---------------- K8: out = relu(P @ h + bias), causal K, fragment-gather DMA ----------------
__global__ __launch_bounds__(256) void k_pv(const __hip_bfloat16* __restrict__ P,
                                            const __hip_bfloat16* __restrict__ ht,
                                            const float* __restrict__ bias,
                                            float* __restrict__ out) {
  int nt = blockIdx.x, mt = blockIdx.y, b = blockIdx.z;
  int m0 = mt*128, n0 = nt*128;
  int Kext = (mt+1)*128;
  __shared__ __hip_bfloat16 Ah[8192], Bh[8192];
  const __hip_bfloat16* Pb = P + (size_t)b*NS*NS;
  int tid = threadIdx.x, wid = tid>>6, lane = tid&63;
  int wm = (wid>>1)*64, wn = (wid&1)*64;
  f32x4 acc[4][4] = {};
  for (int k0 = 0; k0 < Kext; k0 += 64) {
    __syncthreads();
    #pragma unroll
    for (int i = 0; i < 4; ++i) {
      int id = wid*256 + i*64 + lane;
      int kb = id>>9, m = (id>>6)&7, g = (id>>4)&3, rr = id&15;
      int row = m*16 + rr, col = k0 + kb*32 + g*8;
      GLOAD_LDS16(&Pb[(size_t)(m0+row)*NS + col],              &Ah[(wid*256 + i*64)*8]);
      GLOAD_LDS16(&ht[(size_t)(n0+row)*NROW + b*NS + col],     &Bh[(wid*256 + i*64)*8]);
    }
    __syncthreads();
    #pragma unroll
    for (int kb = 0; kb < 2; ++kb) {
      bf16x8 af[4], bf[4];
      #pragma unroll
      for (int qq = 0; qq < 4; ++qq) {
        af[qq] = *(const bf16x8*)&Ah[((kb*8 + (wm>>4) + qq)*64 + lane)*8];
        bf[qq] = *(const bf16x8*)&Bh[((kb*8 + (wn>>4) + qq)*64 + lane)*8];
      }
      #pragma unroll
      for (int mi = 0; mi < 4; ++mi)
        #pragma unroll
        for (int ni = 0; ni < 4; ++ni)
          acc[mi][ni] = __builtin_amdgcn_mfma_f32_16x16x32_bf16(af[mi], bf[ni], acc[mi][ni], 0,0,0);
    }
  }
  int rbase = (lane>>4)*4, col = lane&15;
  #pragma unroll
  for (int mi = 0; mi < 4; ++mi)
    #pragma unroll
    for (int ni = 0; ni < 4; ++ni) {
      int gm = m0 + wm + mi*16 + rbase;
      int gn = n0 + wn + ni*16 + col;
      float bv = bias[gn];
      #pragma unroll
      for (int r2 = 0; r2 < 4; ++r2)
        out[((size_t)b*NS + gm + r2)*NO + gn] = fmaxf(acc[mi][ni][r2] + bv, 0.0f);
    }
}

extern "C" void kernel_launch(void* const* d_in, const int* in_sizes, int n_in,
                              void* d_out, int out_size, void* d_ws, size_t ws_size,
                              hipStream_t stream) {
  (void)in_sizes; (void)n_in; (void)out_size; (void)ws_size;
  const float* x       = (const float*)d_in[0];
  const float* W       = (const float*)d_in[1];
  const float* att_src = (const float*)d_in[2];
  const float* att_dst = (const float*)d_in[3];
  const float* bias    = (const float*)d_in[4];
  float* out = (float*)d_out;

  char* ws = (char*)d_ws;
  // Aliased map (peak 55.25 MB < proven 67.8 MB):
  __hip_bfloat16* yhi   = (__hip_bfloat16*)(ws + 0);           // 16 MB [prep_y..sim]
  __hip_bfloat16* ht    = (__hip_bfloat16*)(ws + 0);           // 16 MB [gemm_ht..pv] (aliases yhi)
  __hip_bfloat16* xb    = (__hip_bfloat16*)(ws + 16777216);    // 16 MB [prep_y..gemm_ht]
  __hip_bfloat16* P     = (__hip_bfloat16*)(ws + 16777216);    // 32 MB [softmax..pv] (aliases xb + free)
  uint16_t*       Mbits = (uint16_t*)     (ws + 50331648);     //  2 MB [sim..softmax]
  unsigned int*   list  = (unsigned int*) (ws + 52428800);     //  2 MB [sim..recheck]
  __hip_bfloat16* Wt    = (__hip_bfloat16*)(ws + 54525952);    // 512 KB [prep_w..gemm_ht]
  float*          rnorm = (float*)        (ws + 55050240);     // 64 KB [prep_y..recheck]
  float*          a_src = (float*)        (ws + 55115776);     // 64 KB [prep_y..softmax]
  float*          a_dst = (float*)        (ws + 55181312);     // 64 KB [prep_y..softmax]
  float*          watt_s= (float*)        (ws + 55246848);     //  2 KB [prep_watt..prep_y]
  float*          watt_d= (float*)        (ws + 55248896);     //  2 KB
  int*            cnt   = (int*)          (ws + 55250944);     // 64 B  [prep_y..recheck]

  k_prep_w   <<<dim3(16,16), dim3(32,32), 0, stream>>>(W, Wt);
  k_prep_watt<<<dim3(2),     dim3(256),   0, stream>>>(W, att_src, att_dst, watt_s, watt_d);
  k_prep_y   <<<dim3(256),   dim3(256),   0, stream>>>(x, xb, yhi, rnorm, a_src, a_dst, watt_s, watt_d, cnt);
  k_sim_mfma <<<dim3(576),   dim3(256),   0, stream>>>(yhi, Mbits, list, cnt);
  k_recheck  <<<dim3(256),   dim3(256),   0, stream>>>(x, rnorm, (uint32_t*)Mbits, list, cnt);
  k_gemm_ht  <<<dim3(128,4), dim3(256),   0, stream>>>(Wt, xb, ht);
  k_softmax  <<<dim3(4096),  dim3(256),   0, stream>>>((const uint32_t*)Mbits, a_src, a_dst, P);
  k_pv       <<<dim3(4,8,16),dim3(256),   0, stream>>>(P, ht, bias, out);
}

// Round 6
// 283.298 us; speedup vs baseline: 1.0361x; 1.0361x over previous
//
#include <hip/hip_runtime.h>
#include <hip/hip_bf16.h>
#include <stdint.h>

#define NB 16
#define NS 1024
#define ND 512
#define NO 512
#define NROW (NB*NS)   // 16384
#define SIM_BAND 8.5e-3f
#define LIST_CAP 524288

typedef float f32x4 __attribute__((ext_vector_type(4)));
typedef __bf16 bf16x8 __attribute__((ext_vector_type(8)));

#define GLOAD_LDS16(g, l) __builtin_amdgcn_global_load_lds( \
    (const __attribute__((address_space(1))) void*)(g), \
    (__attribute__((address_space(3))) void*)(l), 16, 0, 0)

__device__ inline unsigned short f2bs(float f) {
  union { __hip_bfloat16 h; unsigned short u; } c;
  c.h = __float2bfloat16(f);
  return c.u;
}

// ---------------- K1: Wt[o][d] = bf16(W[d][o]) ----------------
__global__ __launch_bounds__(1024) void k_prep_w(const float* __restrict__ W,
                                                 __hip_bfloat16* __restrict__ Wt) {
  __shared__ float tile[32][33];
  int o0 = blockIdx.x*32, d0 = blockIdx.y*32;
  int tx = threadIdx.x, ty = threadIdx.y;
  tile[ty][tx] = W[(size_t)(d0+ty)*NO + o0+tx];
  __syncthreads();
  Wt[(size_t)(o0+ty)*ND + d0+tx] = __float2bfloat16(tile[tx][ty]);
}

// ---------------- K2: watt_s[d] = sum_o W[d][o]*att_src[o]; same for dst ----------------
__global__ __launch_bounds__(256) void k_prep_watt(const float* __restrict__ W,
                                                   const float* __restrict__ att_src,
                                                   const float* __restrict__ att_dst,
                                                   float* __restrict__ watt_s,
                                                   float* __restrict__ watt_d) {
  __shared__ float as_[512], ad_[512];
  int tid = threadIdx.x;
  as_[tid] = att_src[tid]; as_[tid+256] = att_src[tid+256];
  ad_[tid] = att_dst[tid]; ad_[tid+256] = att_dst[tid+256];
  __syncthreads();
  int d = blockIdx.x*256 + tid;
  const float* wr = W + (size_t)d*NO;
  float s = 0.f, dd = 0.f;
  for (int o = 0; o < NO; o += 4) {
    float4 w = *(const float4*)&wr[o];
    s  = fmaf(w.x, as_[o],   fmaf(w.y, as_[o+1], fmaf(w.z, as_[o+2], fmaf(w.w, as_[o+3], s))));
    dd = fmaf(w.x, ad_[o],   fmaf(w.y, ad_[o+1], fmaf(w.z, ad_[o+2], fmaf(w.w, ad_[o+3], dd))));
  }
  watt_s[d] = s;
  watt_d[d] = dd;
}

// ---------------- K3: rnorm, a_src, a_dst, xb (row-major bf16), yhi (fragment-order bf16) ----
__global__ __launch_bounds__(256) void k_prep_y(const float* __restrict__ x,
                                                __hip_bfloat16* __restrict__ xb,
                                                __hip_bfloat16* __restrict__ yhi,
                                                float* __restrict__ rnorm,
                                                float* __restrict__ a_src,
                                                float* __restrict__ a_dst,
                                                const float* __restrict__ watt_s,
                                                const float* __restrict__ watt_d,
                                                int* __restrict__ counter) {
  __shared__ float ws_[512], wd_[512];
  int tid = threadIdx.x, blk = blockIdx.x;
  if (blk == 0 && tid == 0) *counter = 0;
  ws_[tid] = watt_s[tid]; ws_[tid+256] = watt_s[tid+256];
  wd_[tid] = watt_d[tid]; wd_[tid+256] = watt_d[tid+256];
  __syncthreads();
  int r = tid>>2, q = tid&3;
  int grow = blk*64 + r;
  const float* xr = x + (size_t)grow*ND + q*128;
  float ssq = 0.f, as = 0.f, ad = 0.f;
  #pragma unroll
  for (int c8 = 0; c8 < 16; ++c8) {
    float4 v0 = *(const float4*)&xr[c8*8];
    float4 v1 = *(const float4*)&xr[c8*8+4];
    float vv[8] = {v0.x,v0.y,v0.z,v0.w,v1.x,v1.y,v1.z,v1.w};
    union { unsigned short us[8]; uint4 u; } pk;
    #pragma unroll
    for (int j = 0; j < 8; ++j) {
      int c = q*128 + c8*8 + j;
      ssq = fmaf(vv[j], vv[j], ssq);
      as  = fmaf(vv[j], ws_[c], as);
      ad  = fmaf(vv[j], wd_[c], ad);
      pk.us[j] = f2bs(vv[j]);
    }
    *(uint4*)&xb[(size_t)grow*ND + q*128 + c8*8] = pk.u;
  }
  ssq += __shfl_xor(ssq, 1, 64); ssq += __shfl_xor(ssq, 2, 64);
  as  += __shfl_xor(as, 1, 64);  as  += __shfl_xor(as, 2, 64);
  ad  += __shfl_xor(ad, 1, 64);  ad  += __shfl_xor(ad, 2, 64);
  float rn = 1.0f / fmaxf(sqrtf(ssq), 1e-12f);
  if (q == 0) { rnorm[grow] = rn; a_src[grow] = as; a_dst[grow] = ad; }
  int trow = grow & (NS-1), b = grow >> 10;
  int m = (trow>>4)&7, rr = trow&15;
  size_t tilebase = ((size_t)(b*8 + (trow>>7)))*65536;
  #pragma unroll
  for (int c8 = 0; c8 < 16; ++c8) {
    int col = q*128 + c8*8;
    int k0c = col>>6, cc = col&63, kb = cc>>5, g = (cc>>3)&3;
    int id = kb*512 + m*64 + g*16 + rr;
    float4 v0 = *(const float4*)&xr[c8*8];
    float4 v1 = *(const float4*)&xr[c8*8+4];
    float vv[8] = {v0.x,v0.y,v0.z,v0.w,v1.x,v1.y,v1.z,v1.w};
    union { unsigned short us[8]; uint4 u; } pk;
    #pragma unroll
    for (int j = 0; j < 8; ++j) pk.us[j] = f2bs(vv[j]*rn);
    *(uint4*)&yhi[tilebase + (size_t)k0c*8192 + id*8] = pk.u;
  }
}

// ---------------- K4: hi-only MFMA sim, DOUBLE-BUFFERED (issue-next-then-compute) ----------------
#define SIM_STAGE(k0c, buf) do { \
    size_t abase_ = ((size_t)((b*8+ti)*8 + (k0c)))*8192 + wid*2048 + lane*8; \
    _Pragma("unroll") \
    for (int i_ = 0; i_ < 4; ++i_) \
      GLOAD_LDS16(yhi + abase_ + i_*512, &Ah[buf][wid*2048 + i_*512]); \
    if (!diag) { \
      size_t bbase_ = ((size_t)((b*8+tj)*8 + (k0c)))*8192 + wid*2048 + lane*8; \
      _Pragma("unroll") \
      for (int i_ = 0; i_ < 4; ++i_) \
        GLOAD_LDS16(yhi + bbase_ + i_*512, &Bh2[buf][wid*2048 + i_*512]); \
    } \
  } while(0)

__global__ __launch_bounds__(256) void k_sim_mfma(const __hip_bfloat16* __restrict__ yhi,
                                                  uint16_t* __restrict__ Mbits,
                                                  unsigned int* __restrict__ list,
                                                  int* __restrict__ counter) {
  int bid = blockIdx.x;
  int swz = (bid & 7)*72 + (bid >> 3);      // bijective: 576 = 8*72
  int b = swz / 36, p = swz - b*36;
  int ti = 0;
  while ((ti+1)*(ti+2)/2 <= p) ++ti;
  int tj = p - ti*(ti+1)/2;                 // tj <= ti
  __shared__ __hip_bfloat16 Ah[2][8192], Bh2[2][8192];  // 64 KiB
  int tid = threadIdx.x, wid = tid>>6, lane = tid&63;
  int wm = (wid>>1)*64, wn = (wid&1)*64;
  bool diag = (ti == tj);
  f32x4 acc[4][4] = {};
  SIM_STAGE(0, 0);
  __syncthreads();                           // drains vmcnt(0): buf0 ready
  int cur = 0;
  for (int k0c = 0; k0c < 8; ++k0c) {
    if (k0c < 7) SIM_STAGE(k0c+1, cur^1);    // next-tile DMA in flight during compute
    const __hip_bfloat16* Ap = Ah[cur];
    const __hip_bfloat16* Bp = diag ? Ah[cur] : Bh2[cur];
    #pragma unroll
    for (int kb = 0; kb < 2; ++kb) {
      bf16x8 ah[4], bh[4];
      #pragma unroll
      for (int qq = 0; qq < 4; ++qq) {
        ah[qq] = *(const bf16x8*)&Ap[((kb*8 + (wm>>4) + qq)*64 + lane)*8];
        bh[qq] = *(const bf16x8*)&Bp[((kb*8 + (wn>>4) + qq)*64 + lane)*8];
      }
      #pragma unroll
      for (int mi = 0; mi < 4; ++mi)
        #pragma unroll
        for (int ni = 0; ni < 4; ++ni)
          acc[mi][ni] = __builtin_amdgcn_mfma_f32_16x16x32_bf16(ah[mi], bh[ni], acc[mi][ni], 0,0,0);
    }
    __syncthreads();                         // next buffer ready; cur free for overwrite
    cur ^= 1;
  }
  int hi = lane>>4, colL = lane&15;
  #pragma unroll
  for (int mi = 0; mi < 4; ++mi) {
    #pragma unroll
    for (int r2 = 0; r2 < 4; ++r2) {
      int t_g = ti*128 + wm + mi*16 + hi*4 + r2;
      int git = b*NS + t_g;
      #pragma unroll
      for (int ni = 0; ni < 4; ++ni) {
        int s_g = tj*128 + wn + ni*16 + colL;
        float sim = acc[mi][ni][r2];
        bool bit = (s_g == t_g) || (s_g < t_g && sim > 0.9f);
        if (s_g < t_g && fabsf(sim - 0.9f) <= SIM_BAND) {
          int idx = atomicAdd(counter, 1);
          if (idx < LIST_CAP) list[idx] = ((unsigned)b<<20) | ((unsigned)t_g<<10) | (unsigned)s_g;
        }
        unsigned long long bal = __ballot(bit);
        if (colL == 0) {
          uint16_t slice = (uint16_t)((bal >> (hi*16)) & 0xFFFFull);
          Mbits[(size_t)git*64 + ((tj*128 + wn + ni*16)>>4)] = slice;
        }
      }
    }
  }
}

// ---------------- K5: exact f32 recheck of borderline pairs -> fix bits ----------------
__global__ __launch_bounds__(256) void k_recheck(const float* __restrict__ x,
                                                 const float* __restrict__ rnorm,
                                                 uint32_t* __restrict__ Mw,
                                                 const unsigned int* __restrict__ list,
                                                 const int* __restrict__ counter) {
  int n = *counter;
  if (n > LIST_CAP) n = LIST_CAP;
  int gid = blockIdx.x*256 + threadIdx.x;
  for (int i = gid; i < n; i += 256*256) {
    unsigned v = list[i];
    int b = v>>20, t = (v>>10)&1023, s = v&1023;
    const float* xt = x + ((size_t)(b*NS + t))*ND;
    const float* xs = x + ((size_t)(b*NS + s))*ND;
    float4 a4 = {0.f,0.f,0.f,0.f};
    for (int k = 0; k < ND; k += 4) {
      float4 av = *(const float4*)&xt[k];
      float4 bv = *(const float4*)&xs[k];
      a4.x = fmaf(av.x,bv.x,a4.x); a4.y = fmaf(av.y,bv.y,a4.y);
      a4.z = fmaf(av.z,bv.z,a4.z); a4.w = fmaf(av.w,bv.w,a4.w);
    }
    float dot = (a4.x+a4.y)+(a4.z+a4.w);
    float sim = dot * rnorm[b*NS+t] * rnorm[b*NS+s];
    int git = b*NS + t;
    uint32_t bmask = 1u << (s&31);
    if (sim > 0.9f) atomicOr (&Mw[(size_t)git*32 + (s>>5)], bmask);
    else            atomicAnd(&Mw[(size_t)git*32 + (s>>5)], ~bmask);
  }
}

// ---------------- K6: ht[o][i] via MFMA, XOR-swizzled VALU staging (bf16 in) ----------------
__global__ __launch_bounds__(256) void k_gemm_ht(const __hip_bfloat16* __restrict__ Wt,
                                                 const __hip_bfloat16* __restrict__ xb,
                                                 __hip_bfloat16* __restrict__ ht) {
  __shared__ __hip_bfloat16 At[128*64];
  __shared__ __hip_bfloat16 Bt[128*64];
  int m0 = blockIdx.y*128, n0 = blockIdx.x*128;
  int tid = threadIdx.x;
  int wid = tid>>6, lane = tid&63;
  int wm = (wid>>1)*64, wn = (wid&1)*64;
  f32x4 acc[4][4] = {};
  for (int k0 = 0; k0 < ND; k0 += 64) {
    __syncthreads();
    int r = tid>>3, cb = (tid&7)*8;
    #pragma unroll
    for (int p = 0; p < 4; ++p) {
      int R = r + p*32;
      int cbs = cb ^ ((R&7)<<3);
      *(uint4*)&At[R*64 + cbs] = *(const uint4*)&Wt[(size_t)(m0+R)*ND + k0+cb];
      *(uint4*)&Bt[R*64 + cbs] = *(const uint4*)&xb[(size_t)(n0+R)*ND + k0+cb];
    }
    __syncthreads();
    #pragma unroll
    for (int kk = 0; kk < 64; kk += 32) {
      bf16x8 af[4], bfr[4];
      int colk = kk + ((lane>>4)<<3);
      #pragma unroll
      for (int mi = 0; mi < 4; ++mi) {
        int row = wm + (lane&15) + mi*16;
        af[mi] = *(const bf16x8*)&At[row*64 + (colk ^ ((row&7)<<3))];
      }
      #pragma unroll
      for (int ni = 0; ni < 4; ++ni) {
        int row = wn + (lane&15) + ni*16;
        bfr[ni] = *(const bf16x8*)&Bt[row*64 + (colk ^ ((row&7)<<3))];
      }
      #pragma unroll
      for (int mi = 0; mi < 4; ++mi)
        #pragma unroll
        for (int ni = 0; ni < 4; ++ni)
          acc[mi][ni] = __builtin_amdgcn_mfma_f32_16x16x32_bf16(af[mi], bfr[ni], acc[mi][ni], 0,0,0);
    }
  }
  int rbase = (lane>>4)*4, col = lane&15;
  #pragma unroll
  for (int mi = 0; mi < 4; ++mi)
    #pragma unroll
    for (int ni = 0; ni < 4; ++ni) {
      int gm = m0 + wm + mi*16 + rbase;
      int gn = n0 + wn + ni*16 + col;
      #pragma unroll
      for (int r2 = 0; r2 < 4; ++r2)
        ht[(size_t)(gm+r2)*NROW + gn] = __float2bfloat16(acc[mi][ni][r2]);
    }
}

// ---------------- K7: masked softmax from bit mask -> P (bf16), wave per row ----------------
__global__ __launch_bounds__(256) void k_softmax(const uint32_t* __restrict__ Mw,
                                                 const float* __restrict__ a_src,
                                                 const float* __restrict__ a_dst,
                                                 __hip_bfloat16* __restrict__ P) {
  int wid = threadIdx.x>>6, lane = threadIdx.x&63;
  int rowid = blockIdx.x*4 + wid;
  int t = rowid & (NS-1), b = rowid >> 10;
  int n = t + 1;
  const float* as = a_src + b*NS;
  float adv = a_dst[rowid];
  uint32_t w = Mw[(size_t)rowid*32 + (lane>>1)];
  uint32_t bits16 = (lane&1) ? (w>>16) : (w & 0xFFFFu);
  int s0 = lane*16;
  float4 a0 = *(const float4*)&as[s0];
  float4 a1 = *(const float4*)&as[s0+4];
  float4 a2 = *(const float4*)&as[s0+8];
  float4 a3 = *(const float4*)&as[s0+12];
  float va[16] = {a0.x,a0.y,a0.z,a0.w, a1.x,a1.y,a1.z,a1.w,
                  a2.x,a2.y,a2.z,a2.w, a3.x,a3.y,a3.z,a3.w};
  float pr[16];
  float lm = -INFINITY;
  #pragma unroll
  for (int k = 0; k < 16; ++k) {
    int s = s0 + k;
    bool on = (s < n) && ((bits16>>k)&1);
    float vv = adv + va[k];
    float v = (vv > 0.f) ? vv : 0.2f*vv;
    pr[k] = on ? v : -INFINITY;
    lm = fmaxf(lm, pr[k]);
  }
  #pragma unroll
  for (int off = 32; off > 0; off >>= 1) lm = fmaxf(lm, __shfl_xor(lm, off, 64));
  float ls = 0.f;
  #pragma unroll
  for (int k = 0; k < 16; ++k) { pr[k] = __expf(pr[k] - lm); ls += pr[k]; }
  #pragma unroll
  for (int off = 32; off > 0; off >>= 1) ls += __shfl_xor(ls, off, 64);
  float inv = 1.0f / ls;
  int end = ((t >> 7) + 1) << 7;
  if (s0 < end) {
    __hip_bfloat16* Prow = P + (size_t)rowid*NS;
    union { unsigned short us[8]; uint4 u; } w0, w1;
    #pragma unroll
    for (int k = 0; k < 8; ++k)  w0.us[k] = f2bs(pr[k]*inv);
    #pragma unroll
    for (int k = 0; k < 8; ++k)  w1.us[k] = f2bs(pr[k+8]*inv);
    *(uint4*)&Prow[s0]   = w0.u;
    *(uint4*)&Prow[s0+8] = w1.u;
  }
}

// ---------------- K8: out = relu(P @ h + bias), causal K, XOR-swizzled VALU staging ----------------
__global__ __launch_bounds__(256) void k_pv(const __hip_bfloat16* __restrict__ P,
                                            const __hip_bfloat16* __restrict__ ht,
                                            const float* __restrict__ bias,
                                            float* __restrict__ out) {
  int nt = blockIdx.x, mt = blockIdx.y, b = blockIdx.z;
  int m0 = mt*128, n0 = nt*128;
  int Kext = (mt+1)*128;
  __shared__ __hip_bfloat16 At[128*64];
  __shared__ __hip_bfloat16 Bt[128*64];
  const __hip_bfloat16* Pb = P + (size_t)b*NS*NS;
  int tid = threadIdx.x;
  int wid = tid>>6, lane = tid&63;
  int wm = (wid>>1)*64, wn = (wid&1)*64;
  f32x4 acc[4][4] = {};
  for (int k0 = 0; k0 < Kext; k0 += 64) {
    __syncthreads();
    int r = tid>>3, cb = (tid&7)*8;
    #pragma unroll
    for (int p = 0; p < 4; ++p) {
      int R = r + p*32;
      int cbs = cb ^ ((R&7)<<3);
      *(uint4*)&At[R*64 + cbs] = *(const uint4*)&Pb[(size_t)(m0+R)*NS + k0+cb];
      *(uint4*)&Bt[R*64 + cbs] = *(const uint4*)&ht[(size_t)(n0+R)*NROW + b*NS + k0+cb];
    }
    __syncthreads();
    #pragma unroll
    for (int kk = 0; kk < 64; kk += 32) {
      bf16x8 af[4], bfr[4];
      int colk = kk + ((lane>>4)<<3);
      #pragma unroll
      for (int mi = 0; mi < 4; ++mi) {
        int row = wm + (lane&15) + mi*16;
        af[mi] = *(const bf16x8*)&At[row*64 + (colk ^ ((row&7)<<3))];
      }
      #pragma unroll
      for (int ni = 0; ni < 4; ++ni) {
        int row = wn + (lane&15) + ni*16;
        bfr[ni] = *(const bf16x8*)&Bt[row*64 + (colk ^ ((row&7)<<3))];
      }
      #pragma unroll
      for (int mi = 0; mi < 4; ++mi)
        #pragma unroll
        for (int ni = 0; ni < 4; ++ni)
          acc[mi][ni] = __builtin_amdgcn_mfma_f32_16x16x32_bf16(af[mi], bfr[ni], acc[mi][ni], 0,0,0);
    }
  }
  int rbase = (lane>>4)*4, col = lane&15;
  #pragma unroll
  for (int mi = 0; mi < 4; ++mi)
    #pragma unroll
    for (int ni = 0; ni < 4; ++ni) {
      int gm = m0 + wm + mi*16 + rbase;
      int gn = n0 + wn + ni*16 + col;
      float bv = bias[gn];
      #pragma unroll
      for (int r2 = 0; r2 < 4; ++r2)
        out[((size_t)b*NS + gm + r2)*NO + gn] = fmaxf(acc[mi][ni][r2] + bv, 0.0f);
    }
}

extern "C" void kernel_launch(void* const* d_in, const int* in_sizes, int n_in,
                              void* d_out, int out_size, void* d_ws, size_t ws_size,
                              hipStream_t stream) {
  (void)in_sizes; (void)n_in; (void)out_size; (void)ws_size;
  const float* x       = (const float*)d_in[0];
  const float* W       = (const float*)d_in[1];
  const float* att_src = (const float*)d_in[2];
  const float* att_dst = (const float*)d_in[3];
  const float* bias    = (const float*)d_in[4];
  float* out = (float*)d_out;

  char* ws = (char*)d_ws;
  // Aliased map (peak ~52.7 MiB < proven 67.8 MB budget):
  __hip_bfloat16* yhi   = (__hip_bfloat16*)(ws + 0);           // 16 MB [prep_y..sim]
  __hip_bfloat16* ht    = (__hip_bfloat16*)(ws + 0);           // 16 MB [gemm_ht..pv] (aliases yhi)
  __hip_bfloat16* xb    = (__hip_bfloat16*)(ws + 16777216);    // 16 MB [prep_y..gemm_ht]
  __hip_bfloat16* P     = (__hip_bfloat16*)(ws + 16777216);    // 32 MB [softmax..pv] (aliases xb)
  uint16_t*       Mbits = (uint16_t*)     (ws + 50331648);     //  2 MB [sim..softmax]
  unsigned int*   list  = (unsigned int*) (ws + 52428800);     //  2 MB [sim..recheck]
  __hip_bfloat16* Wt    = (__hip_bfloat16*)(ws + 54525952);    // 512 KB [prep_w..gemm_ht]
  float*          rnorm = (float*)        (ws + 55050240);     // 64 KB [prep_y..recheck]
  float*          a_src = (float*)        (ws + 55115776);     // 64 KB [prep_y..softmax]
  float*          a_dst = (float*)        (ws + 55181312);     // 64 KB [prep_y..softmax]
  float*          watt_s= (float*)        (ws + 55246848);     //  2 KB [prep_watt..prep_y]
  float*          watt_d= (float*)        (ws + 55248896);     //  2 KB
  int*            cnt   = (int*)          (ws + 55250944);     // 64 B  [prep_y..recheck]

  k_prep_w   <<<dim3(16,16), dim3(32,32), 0, stream>>>(W, Wt);
  k_prep_watt<<<dim3(2),     dim3(256),   0, stream>>>(W, att_src, att_dst, watt_s, watt_d);
  k_prep_y   <<<dim3(256),   dim3(256),   0, stream>>>(x, xb, yhi, rnorm, a_src, a_dst, watt_s, watt_d, cnt);
  k_sim_mfma <<<dim3(576),   dim3(256),   0, stream>>>(yhi, Mbits, list, cnt);
  k_recheck  <<<dim3(256),   dim3(256),   0, stream>>>(x, rnorm, (uint32_t*)Mbits, list, cnt);
  k_gemm_ht  <<<dim3(128,4), dim3(256),   0, stream>>>(Wt, xb, ht);
  k_softmax  <<<dim3(4096),  dim3(256),   0, stream>>>((const uint32_t*)Mbits, a_src, a_dst, P);
  k_pv       <<<dim3(4,8,16),dim3(256),   0, stream>>>(P, ht, bias, out);
}

// Round 7
// 183.152 us; speedup vs baseline: 1.6027x; 1.5468x over previous
//
#include <hip/hip_runtime.h>
#include <hip/hip_bf16.h>
#include <stdint.h>

#define NB 16
#define NS 1024
#define ND 512
#define NO 512
#define NROW (NB*NS)   // 16384
#define SIM_BAND 2e-3f
#define LIST_CAP 1048576

typedef float f32x4 __attribute__((ext_vector_type(4)));
typedef __bf16 bf16x8 __attribute__((ext_vector_type(8)));

#define GLOAD_LDS16(g, l) __builtin_amdgcn_global_load_lds( \
    (const __attribute__((address_space(1))) void*)(g), \
    (__attribute__((address_space(3))) void*)(l), 16, 0, 0)

__device__ inline unsigned short f2bs(float f) {
  union { __hip_bfloat16 h; unsigned short u; } c;
  c.h = __float2bfloat16(f);
  return c.u;
}

// ---------------- K1: Wt[o][d] = bf16(W[d][o]) ----------------
__global__ __launch_bounds__(1024) void k_prep_w(const float* __restrict__ W,
                                                 __hip_bfloat16* __restrict__ Wt) {
  __shared__ float tile[32][33];
  int o0 = blockIdx.x*32, d0 = blockIdx.y*32;
  int tx = threadIdx.x, ty = threadIdx.y;
  tile[ty][tx] = W[(size_t)(d0+ty)*NO + o0+tx];
  __syncthreads();
  Wt[(size_t)(o0+ty)*ND + d0+tx] = __float2bfloat16(tile[tx][ty]);
}

// ---------------- K2: watt_s[d] = sum_o W[d][o]*att_src[o]; same for dst ----------------
__global__ __launch_bounds__(256) void k_prep_watt(const float* __restrict__ W,
                                                   const float* __restrict__ att_src,
                                                   const float* __restrict__ att_dst,
                                                   float* __restrict__ watt_s,
                                                   float* __restrict__ watt_d) {
  __shared__ float as_[512], ad_[512];
  int tid = threadIdx.x;
  as_[tid] = att_src[tid]; as_[tid+256] = att_src[tid+256];
  ad_[tid] = att_dst[tid]; ad_[tid+256] = att_dst[tid+256];
  __syncthreads();
  int d = blockIdx.x*256 + tid;
  const float* wr = W + (size_t)d*NO;
  float s = 0.f, dd = 0.f;
  for (int o = 0; o < NO; o += 4) {
    float4 w = *(const float4*)&wr[o];
    s  = fmaf(w.x, as_[o],   fmaf(w.y, as_[o+1], fmaf(w.z, as_[o+2], fmaf(w.w, as_[o+3], s))));
    dd = fmaf(w.x, ad_[o],   fmaf(w.y, ad_[o+1], fmaf(w.z, ad_[o+2], fmaf(w.w, ad_[o+3], dd))));
  }
  watt_s[d] = s;
  watt_d[d] = dd;
}

// ---------------- K3: rnorm + a_src/a_dst (via watt) + trunc-split yhi/ylo fragment-order ----
// yhi/ylo layout: elem off ((b*8+tblk)*8 + k0c)*8192 + id*8, id = kb*512 + m*64 + g*16 + r
__global__ __launch_bounds__(256) void k_prep_y(const float* __restrict__ x,
                                                __hip_bfloat16* __restrict__ yhi,
                                                __hip_bfloat16* __restrict__ ylo,
                                                float* __restrict__ rnorm,
                                                float* __restrict__ a_src,
                                                float* __restrict__ a_dst,
                                                const float* __restrict__ watt_s,
                                                const float* __restrict__ watt_d,
                                                int* __restrict__ counter) {
  __shared__ float ws_[512], wd_[512];
  int tid = threadIdx.x, blk = blockIdx.x;
  if (blk == 0 && tid == 0) *counter = 0;
  ws_[tid] = watt_s[tid]; ws_[tid+256] = watt_s[tid+256];
  wd_[tid] = watt_d[tid]; wd_[tid+256] = watt_d[tid+256];
  __syncthreads();
  int r = tid>>2, q = tid&3;            // 64 rows/block, 4 lanes/row (128 cols each)
  int grow = blk*64 + r;                // grid 256
  const float* xr = x + (size_t)grow*ND + q*128;
  // pass 1: ssq + logits dots
  float ssq = 0.f, as = 0.f, ad = 0.f;
  #pragma unroll
  for (int c8 = 0; c8 < 16; ++c8) {
    float4 v0 = *(const float4*)&xr[c8*8];
    float4 v1 = *(const float4*)&xr[c8*8+4];
    float vv[8] = {v0.x,v0.y,v0.z,v0.w,v1.x,v1.y,v1.z,v1.w};
    #pragma unroll
    for (int j = 0; j < 8; ++j) {
      int c = q*128 + c8*8 + j;
      ssq = fmaf(vv[j], vv[j], ssq);
      as  = fmaf(vv[j], ws_[c], as);
      ad  = fmaf(vv[j], wd_[c], ad);
    }
  }
  ssq += __shfl_xor(ssq, 1, 64); ssq += __shfl_xor(ssq, 2, 64);
  as  += __shfl_xor(as, 1, 64);  as  += __shfl_xor(as, 2, 64);
  ad  += __shfl_xor(ad, 1, 64);  ad  += __shfl_xor(ad, 2, 64);
  float rn = 1.0f / fmaxf(sqrtf(ssq), 1e-12f);
  if (q == 0) { rnorm[grow] = rn; a_src[grow] = as; a_dst[grow] = ad; }
  // pass 2: yhi/ylo (normalized, trunc split) in fragment order
  int trow = grow & (NS-1), b = grow >> 10;
  int m = (trow>>4)&7, rr = trow&15;
  size_t tilebase = ((size_t)(b*8 + (trow>>7)))*65536;
  #pragma unroll
  for (int c8 = 0; c8 < 16; ++c8) {
    int col = q*128 + c8*8;
    int k0c = col>>6, cc = col&63, kb = cc>>5, g = (cc>>3)&3;
    int id = kb*512 + m*64 + g*16 + rr;
    size_t off = tilebase + (size_t)k0c*8192 + id*8;
    float4 v0 = *(const float4*)&xr[c8*8];
    float4 v1 = *(const float4*)&xr[c8*8+4];
    float vv[8] = {v0.x,v0.y,v0.z,v0.w,v1.x,v1.y,v1.z,v1.w};
    union { unsigned short us[8]; uint4 u; } ph, pl;
    #pragma unroll
    for (int j = 0; j < 8; ++j) {
      float y = vv[j]*rn;
      unsigned yb = __float_as_uint(y);
      float hf = __uint_as_float(yb & 0xFFFF0000u);
      float lf = y - hf;                       // exact
      ph.us[j] = (unsigned short)(yb >> 16);
      pl.us[j] = (unsigned short)(__float_as_uint(lf) >> 16);
    }
    *(uint4*)&yhi[off] = ph.u;
    *(uint4*)&ylo[off] = pl.u;
  }
}

// ---------------- K4: sim via split-bf16 MFMA (3-term), gload_lds staging -> byte mask ----------------
// Proven 43.9us structure (round-4 bench). grid 576 = 36 tile-pairs x 16 batches, XCD-swizzled.
__global__ __launch_bounds__(256) void k_sim_mfma(const __hip_bfloat16* __restrict__ yhi,
                                                  const __hip_bfloat16* __restrict__ ylo,
                                                  uint8_t* __restrict__ Mmask,
                                                  unsigned int* __restrict__ list,
                                                  int* __restrict__ counter) {
  int bid = blockIdx.x;
  int swz = (bid & 7)*72 + (bid >> 3);      // bijective: 576 = 8*72
  int b = swz / 36, p = swz - b*36;
  int ti = 0;
  while ((ti+1)*(ti+2)/2 <= p) ++ti;
  int tj = p - ti*(ti+1)/2;                 // tj <= ti
  __shared__ __hip_bfloat16 Ahi[8192], Alo[8192], Bhi[8192], Blo[8192];
  int tid = threadIdx.x, wid = tid>>6, lane = tid&63;
  int wm = (wid>>1)*64, wn = (wid&1)*64;
  bool diag = (ti == tj);
  const __hip_bfloat16* Bh = diag ? Ahi : Bhi;
  const __hip_bfloat16* Bl = diag ? Alo : Blo;
  f32x4 acc[4][4] = {};
  for (int k0c = 0; k0c < 8; ++k0c) {
    __syncthreads();
    size_t abase = ((size_t)((b*8+ti)*8 + k0c))*8192 + wid*2048 + lane*8;
    size_t bbase = ((size_t)((b*8+tj)*8 + k0c))*8192 + wid*2048 + lane*8;
    int lb = wid*2048;
    #pragma unroll
    for (int i = 0; i < 4; ++i) {
      GLOAD_LDS16(yhi + abase + i*512, &Ahi[lb + i*512]);
      GLOAD_LDS16(ylo + abase + i*512, &Alo[lb + i*512]);
    }
    if (!diag) {
      #pragma unroll
      for (int i = 0; i < 4; ++i) {
        GLOAD_LDS16(yhi + bbase + i*512, &Bhi[lb + i*512]);
        GLOAD_LDS16(ylo + bbase + i*512, &Blo[lb + i*512]);
      }
    }
    __syncthreads();
    #pragma unroll
    for (int kb = 0; kb < 2; ++kb) {
      bf16x8 ah[4], al[4], bh[4], bl[4];
      #pragma unroll
      for (int q = 0; q < 4; ++q) {
        int aoff = ((kb*8 + (wm>>4) + q)*64 + lane)*8;
        ah[q] = *(const bf16x8*)&Ahi[aoff];
        al[q] = *(const bf16x8*)&Alo[aoff];
        int boff = ((kb*8 + (wn>>4) + q)*64 + lane)*8;
        bh[q] = *(const bf16x8*)&Bh[boff];
        bl[q] = *(const bf16x8*)&Bl[boff];
      }
      #pragma unroll
      for (int mi = 0; mi < 4; ++mi)
        #pragma unroll
        for (int ni = 0; ni < 4; ++ni) {
          acc[mi][ni] = __builtin_amdgcn_mfma_f32_16x16x32_bf16(ah[mi], bh[ni], acc[mi][ni], 0,0,0);
          acc[mi][ni] = __builtin_amdgcn_mfma_f32_16x16x32_bf16(ah[mi], bl[ni], acc[mi][ni], 0,0,0);
          acc[mi][ni] = __builtin_amdgcn_mfma_f32_16x16x32_bf16(al[mi], bh[ni], acc[mi][ni], 0,0,0);
        }
    }
  }
  int rbase = (lane>>4)*4, colL = lane&15;
  #pragma unroll
  for (int mi = 0; mi < 4; ++mi) {
    #pragma unroll
    for (int r2 = 0; r2 < 4; ++r2) {
      int t_g = ti*128 + wm + mi*16 + rbase + r2;
      int git = b*NS + t_g;
      uint8_t* Mrow = Mmask + (size_t)git*NS;
      #pragma unroll
      for (int ni = 0; ni < 4; ++ni) {
        int s_g = tj*128 + wn + ni*16 + colL;
        if (s_g > t_g) continue;
        float sim = acc[mi][ni][r2];
        bool edge = (s_g == t_g) || (sim > 0.9f);
        if (s_g < t_g && fabsf(sim - 0.9f) <= SIM_BAND) {
          int idx = atomicAdd(counter, 1);
          if (idx < LIST_CAP) list[idx] = ((unsigned)b<<20) | ((unsigned)t_g<<10) | (unsigned)s_g;
        }
        Mrow[s_g] = edge ? 1 : 0;
      }
    }
  }
}

// ---------------- K5: exact f32 recheck of borderline pairs -> fix mask bytes ----------------
__global__ __launch_bounds__(256) void k_recheck(const float* __restrict__ x,
                                                 const float* __restrict__ rnorm,
                                                 uint8_t* __restrict__ Mmask,
                                                 const unsigned int* __restrict__ list,
                                                 const int* __restrict__ counter) {
  int n = *counter;
  if (n > LIST_CAP) n = LIST_CAP;
  int gid = blockIdx.x*256 + threadIdx.x;
  for (int i = gid; i < n; i += 256*256) {
    unsigned v = list[i];
    int b = v>>20, t = (v>>10)&1023, s = v&1023;
    const float* xt = x + ((size_t)(b*NS + t))*ND;
    const float* xs = x + ((size_t)(b*NS + s))*ND;
    float4 a4 = {0.f,0.f,0.f,0.f};
    for (int k = 0; k < ND; k += 4) {
      float4 av = *(const float4*)&xt[k];
      float4 bv = *(const float4*)&xs[k];
      a4.x = fmaf(av.x,bv.x,a4.x); a4.y = fmaf(av.y,bv.y,a4.y);
      a4.z = fmaf(av.z,bv.z,a4.z); a4.w = fmaf(av.w,bv.w,a4.w);
    }
    float dot = (a4.x+a4.y)+(a4.z+a4.w);
    float sim = dot * rnorm[b*NS+t] * rnorm[b*NS+s];
    Mmask[((size_t)(b*NS+t))*NS + s] = (sim > 0.9f) ? 1 : 0;
  }
}

// ---------------- K6: ht[o][i] via MFMA, XOR-swizzled VALU staging (f32 in, cast) ----------------
__global__ __launch_bounds__(256) void k_gemm_ht(const __hip_bfloat16* __restrict__ Wt,
                                                 const float* __restrict__ xg,
                                                 __hip_bfloat16* __restrict__ ht) {
  __shared__ __hip_bfloat16 At[128*64];
  __shared__ __hip_bfloat16 Bt[128*64];
  int m0 = blockIdx.y*128, n0 = blockIdx.x*128;
  int tid = threadIdx.x;
  int wid = tid>>6, lane = tid&63;
  int wm = (wid>>1)*64, wn = (wid&1)*64;
  f32x4 acc[4][4] = {};
  for (int k0 = 0; k0 < ND; k0 += 64) {
    __syncthreads();
    int r = tid>>3, cb = (tid&7)*8;
    #pragma unroll
    for (int p = 0; p < 4; ++p) {
      int R = r + p*32;
      int cbs = cb ^ ((R&7)<<3);
      *(uint4*)&At[R*64 + cbs] = *(const uint4*)&Wt[(size_t)(m0+R)*ND + k0+cb];
      const float* src = &xg[(size_t)(n0+R)*ND + k0+cb];
      float4 v0 = *(const float4*)src;
      float4 v1 = *(const float4*)(src+4);
      union { unsigned short us[8]; uint4 q; } pk;
      pk.us[0]=f2bs(v0.x); pk.us[1]=f2bs(v0.y); pk.us[2]=f2bs(v0.z); pk.us[3]=f2bs(v0.w);
      pk.us[4]=f2bs(v1.x); pk.us[5]=f2bs(v1.y); pk.us[6]=f2bs(v1.z); pk.us[7]=f2bs(v1.w);
      *(uint4*)&Bt[R*64 + cbs] = pk.q;
    }
    __syncthreads();
    #pragma unroll
    for (int kk = 0; kk < 64; kk += 32) {
      bf16x8 af[4], bfr[4];
      int colk = kk + ((lane>>4)<<3);
      #pragma unroll
      for (int mi = 0; mi < 4; ++mi) {
        int row = wm + (lane&15) + mi*16;
        af[mi] = *(const bf16x8*)&At[row*64 + (colk ^ ((row&7)<<3))];
      }
      #pragma unroll
      for (int ni = 0; ni < 4; ++ni) {
        int row = wn + (lane&15) + ni*16;
        bfr[ni] = *(const bf16x8*)&Bt[row*64 + (colk ^ ((row&7)<<3))];
      }
      #pragma unroll
      for (int mi = 0; mi < 4; ++mi)
        #pragma unroll
        for (int ni = 0; ni < 4; ++ni)
          acc[mi][ni] = __builtin_amdgcn_mfma_f32_16x16x32_bf16(af[mi], bfr[ni], acc[mi][ni], 0,0,0);
    }
  }
  int rbase = (lane>>4)*4, col = lane&15;
  #pragma unroll
  for (int mi = 0; mi < 4; ++mi)
    #pragma unroll
    for (int ni = 0; ni < 4; ++ni) {
      int gm = m0 + wm + mi*16 + rbase;
      int gn = n0 + wn + ni*16 + col;
      #pragma unroll
      for (int r2 = 0; r2 < 4; ++r2)
        ht[(size_t)(gm+r2)*NROW + gn] = __float2bfloat16(acc[mi][ni][r2]);
    }
}

// ---------------- K7: masked softmax from byte mask -> P (bf16), zero-fill to 128 ----------------
__global__ __launch_bounds__(256) void k_softmax(const uint8_t* __restrict__ Mmask,
                                                 const float* __restrict__ a_src,
                                                 const float* __restrict__ a_dst,
                                                 __hip_bfloat16* __restrict__ P) {
  int rowid = blockIdx.x;
  int t = rowid & (NS-1);
  int b = rowid >> 10;
  const uint8_t* Mrow = Mmask + (size_t)rowid * NS;
  __hip_bfloat16* Prow = P + (size_t)rowid * NS;
  const float* as = a_src + b*NS;
  float adv = a_dst[rowid];
  int tid = threadIdx.x;
  int n = t + 1;
  float v[4];
  float lm = -INFINITY;
  #pragma unroll
  for (int k = 0; k < 4; ++k) {
    int s = tid + k*256;
    v[k] = -INFINITY;
    if (s < n && Mrow[s]) {
      float vv = adv + as[s];
      v[k] = (vv > 0.f) ? vv : 0.2f*vv;
    }
    lm = fmaxf(lm, v[k]);
  }
  __shared__ float red1[4];
  __shared__ float red2[4];
  #pragma unroll
  for (int off = 32; off > 0; off >>= 1) lm = fmaxf(lm, __shfl_xor(lm, off, 64));
  int wid = tid>>6, lane = tid&63;
  if (lane == 0) red1[wid] = lm;
  __syncthreads();
  float m = fmaxf(fmaxf(red1[0],red1[1]), fmaxf(red1[2],red1[3]));
  float ls = 0.f;
  #pragma unroll
  for (int k = 0; k < 4; ++k) if (v[k] > -INFINITY) ls += __expf(v[k] - m);
  #pragma unroll
  for (int off = 32; off > 0; off >>= 1) ls += __shfl_xor(ls, off, 64);
  if (lane == 0) red2[wid] = ls;
  __syncthreads();
  float l = red2[0]+red2[1]+red2[2]+red2[3];
  float inv = 1.0f / l;
  #pragma unroll
  for (int k = 0; k < 4; ++k) {
    int s = tid + k*256;
    if (s < n) Prow[s] = __float2bfloat16((v[k] > -INFINITY) ? __expf(v[k]-m)*inv : 0.0f);
  }
  int end = ((t >> 7) + 1) << 7;
  for (int s = n + tid; s < end; s += 256) Prow[s] = __float2bfloat16(0.0f);
}

// ---------------- K8: out = relu(P @ h + bias), causal K, XOR-swizzled VALU staging ----------------
__global__ __launch_bounds__(256) void k_pv(const __hip_bfloat16* __restrict__ P,
                                            const __hip_bfloat16* __restrict__ ht,
                                            const float* __restrict__ bias,
                                            float* __restrict__ out) {
  int nt = blockIdx.x, mt = blockIdx.y, b = blockIdx.z;
  int m0 = mt*128, n0 = nt*128;
  int Kext = (mt+1)*128;
  __shared__ __hip_bfloat16 At[128*64];
  __shared__ __hip_bfloat16 Bt[128*64];
  const __hip_bfloat16* Pb = P + (size_t)b*NS*NS;
  int tid = threadIdx.x;
  int wid = tid>>6, lane = tid&63;
  int wm = (wid>>1)*64, wn = (wid&1)*64;
  f32x4 acc[4][4] = {};
  for (int k0 = 0; k0 < Kext; k0 += 64) {
    __syncthreads();
    int r = tid>>3, cb = (tid&7)*8;
    #pragma unroll
    for (int p = 0; p < 4; ++p) {
      int R = r + p*32;
      int cbs = cb ^ ((R&7)<<3);
      *(uint4*)&At[R*64 + cbs] = *(const uint4*)&Pb[(size_t)(m0+R)*NS + k0+cb];
      *(uint4*)&Bt[R*64 + cbs] = *(const uint4*)&ht[(size_t)(n0+R)*NROW + b*NS + k0+cb];
    }
    __syncthreads();
    #pragma unroll
    for (int kk = 0; kk < 64; kk += 32) {
      bf16x8 af[4], bfr[4];
      int colk = kk + ((lane>>4)<<3);
      #pragma unroll
      for (int mi = 0; mi < 4; ++mi) {
        int row = wm + (lane&15) + mi*16;
        af[mi] = *(const bf16x8*)&At[row*64 + (colk ^ ((row&7)<<3))];
      }
      #pragma unroll
      for (int ni = 0; ni < 4; ++ni) {
        int row = wn + (lane&15) + ni*16;
        bfr[ni] = *(const bf16x8*)&Bt[row*64 + (colk ^ ((row&7)<<3))];
      }
      #pragma unroll
      for (int mi = 0; mi < 4; ++mi)
        #pragma unroll
        for (int ni = 0; ni < 4; ++ni)
          acc[mi][ni] = __builtin_amdgcn_mfma_f32_16x16x32_bf16(af[mi], bfr[ni], acc[mi][ni], 0,0,0);
    }
  }
  int rbase = (lane>>4)*4, col = lane&15;
  #pragma unroll
  for (int mi = 0; mi < 4; ++mi)
    #pragma unroll
    for (int ni = 0; ni < 4; ++ni) {
      int gm = m0 + wm + mi*16 + rbase;
      int gn = n0 + wn + ni*16 + col;
      float bv = bias[gn];
      #pragma unroll
      for (int r2 = 0; r2 < 4; ++r2)
        out[((size_t)b*NS + gm + r2)*NO + gn] = fmaxf(acc[mi][ni][r2] + bv, 0.0f);
    }
}

extern "C" void kernel_launch(void* const* d_in, const int* in_sizes, int n_in,
                              void* d_out, int out_size, void* d_ws, size_t ws_size,
                              hipStream_t stream) {
  (void)in_sizes; (void)n_in; (void)out_size; (void)ws_size;
  const float* x       = (const float*)d_in[0];
  const float* W       = (const float*)d_in[1];
  const float* att_src = (const float*)d_in[2];
  const float* att_dst = (const float*)d_in[3];
  const float* bias    = (const float*)d_in[4];
  float* out = (float*)d_out;

  char* ws = (char*)d_ws;
  // Proven 67.8MB map (r1). Lifetimes:
  __hip_bfloat16* yhi   = (__hip_bfloat16*)(ws + 0);           // 16 MB [prep_y..sim]
  __hip_bfloat16* ylo   = (__hip_bfloat16*)(ws + 16777216);    // 16 MB [prep_y..sim]
  __hip_bfloat16* P     = (__hip_bfloat16*)(ws + 0);           // 32 MB [softmax..pv] (aliases yhi/ylo)
  int*            cnt   = (int*)          (ws + 33554432);     // 16 B  [prep_y..recheck]
  unsigned int*   list  = (unsigned int*) (ws + 33554448);     //  4 MB [sim..recheck]
  __hip_bfloat16* ht    = (__hip_bfloat16*)(ws + 33554432);    // 16 MB [gemm_ht..pv] (aliases cnt/list)
  uint8_t*        Mmask = (uint8_t*)      (ws + 50331648);     // 16 MB [sim..softmax]
  float*          watt_s= (float*)        (ws + 50331648);     //  2 KB [prep_watt..prep_y] (inside Mmask, dead before sim)
  float*          watt_d= (float*)        (ws + 50333696);     //  2 KB
  __hip_bfloat16* Wt    = (__hip_bfloat16*)(ws + 67108864);    // 512 KB [prep_w..gemm_ht]
  float*          rnorm = (float*)        (ws + 67633152);     // 64 KB [prep_y..recheck]
  float*          a_src = (float*)        (ws + 67698688);     // 64 KB [prep_y..softmax]
  float*          a_dst = (float*)        (ws + 67764224);     // 64 KB [prep_y..softmax]

  k_prep_w   <<<dim3(16,16), dim3(32,32), 0, stream>>>(W, Wt);
  k_prep_watt<<<dim3(2),     dim3(256),   0, stream>>>(W, att_src, att_dst, watt_s, watt_d);
  k_prep_y   <<<dim3(256),   dim3(256),   0, stream>>>(x, yhi, ylo, rnorm, a_src, a_dst, watt_s, watt_d, cnt);
  k_sim_mfma <<<dim3(576),   dim3(256),   0, stream>>>(yhi, ylo, Mmask, list, cnt);
  k_recheck  <<<dim3(256),   dim3(256),   0, stream>>>(x, rnorm, Mmask, list, cnt);
  k_gemm_ht  <<<dim3(128,4), dim3(256),   0, stream>>>(Wt, x, ht);
  k_softmax  <<<dim3(NROW),  dim3(256),   0, stream>>>(Mmask, a_src, a_dst, P);
  k_pv       <<<dim3(4,8,16),dim3(256),   0, stream>>>(P, ht, bias, out);
}

// Round 9
// 172.305 us; speedup vs baseline: 1.7036x; 1.0630x over previous
//
#include <hip/hip_runtime.h>
#include <hip/hip_bf16.h>
#include <stdint.h>

#define NB 16
#define NS 1024
#define ND 512
#define NO 512
#define NROW (NB*NS)   // 16384
#define SIM_BAND 2e-3f
#define LIST_CAP 1048576

typedef float f32x4 __attribute__((ext_vector_type(4)));
typedef __bf16 bf16x8 __attribute__((ext_vector_type(8)));

#define GLOAD_LDS16(g, l) __builtin_amdgcn_global_load_lds( \
    (const __attribute__((address_space(1))) void*)(g), \
    (__attribute__((address_space(3))) void*)(l), 16, 0, 0)

__device__ inline unsigned short f2bs(float f) {
  union { __hip_bfloat16 h; unsigned short u; } c;
  c.h = __float2bfloat16(f);
  return c.u;
}

// ---------------- K1: Wf = bf16(W^T) in fragment-order tiles ----------------
// tile (mt in 0..3, k0c in 0..7): elem ((mt*8+k0c)*8192 + id*8 + j) holds
// W[d][o] with o = mt*128 + m*16 + r, d = k0c*64 + kb*32 + g*8 + j, id = kb*512+m*64+g*16+r
__global__ __launch_bounds__(256) void k_prep_wfrag(const float* __restrict__ W,
                                                    __hip_bfloat16* __restrict__ Wf) {
  int mt = blockIdx.x, k0c = blockIdx.y;   // grid (4,8)
  int tid = threadIdx.x;
  size_t base = ((size_t)(mt*8 + k0c))*8192;
  #pragma unroll
  for (int pp = 0; pp < 4; ++pp) {
    int id = pp*256 + tid;
    int kb = id>>9, m = (id>>6)&7, g = (id>>4)&3, r = id&15;
    int o = mt*128 + m*16 + r;
    int d0 = k0c*64 + kb*32 + g*8;
    union { unsigned short us[8]; uint4 u; } pk;
    #pragma unroll
    for (int j = 0; j < 8; ++j) pk.us[j] = f2bs(W[(size_t)(d0+j)*NO + o]);
    *(uint4*)&Wf[base + id*8] = pk.u;
  }
}

// ---------------- K2: watt_s[d] = sum_o W[d][o]*att_src[o]; same for dst ----------------
__global__ __launch_bounds__(256) void k_prep_watt(const float* __restrict__ W,
                                                   const float* __restrict__ att_src,
                                                   const float* __restrict__ att_dst,
                                                   float* __restrict__ watt_s,
                                                   float* __restrict__ watt_d) {
  __shared__ float as_[512], ad_[512];
  int tid = threadIdx.x;
  as_[tid] = att_src[tid]; as_[tid+256] = att_src[tid+256];
  ad_[tid] = att_dst[tid]; ad_[tid+256] = att_dst[tid+256];
  __syncthreads();
  int d = blockIdx.x*256 + tid;
  const float* wr = W + (size_t)d*NO;
  float s = 0.f, dd = 0.f;
  for (int o = 0; o < NO; o += 4) {
    float4 w = *(const float4*)&wr[o];
    s  = fmaf(w.x, as_[o],   fmaf(w.y, as_[o+1], fmaf(w.z, as_[o+2], fmaf(w.w, as_[o+3], s))));
    dd = fmaf(w.x, ad_[o],   fmaf(w.y, ad_[o+1], fmaf(w.z, ad_[o+2], fmaf(w.w, ad_[o+3], dd))));
  }
  watt_s[d] = s;
  watt_d[d] = dd;
}

// ---------------- K3: rnorm + a_src/a_dst (via watt) + trunc-split yhi/ylo fragment-order ----
__global__ __launch_bounds__(256) void k_prep_y(const float* __restrict__ x,
                                                __hip_bfloat16* __restrict__ yhi,
                                                __hip_bfloat16* __restrict__ ylo,
                                                float* __restrict__ rnorm,
                                                float* __restrict__ a_src,
                                                float* __restrict__ a_dst,
                                                const float* __restrict__ watt_s,
                                                const float* __restrict__ watt_d,
                                                int* __restrict__ counter) {
  __shared__ float ws_[512], wd_[512];
  int tid = threadIdx.x, blk = blockIdx.x;
  if (blk == 0 && tid == 0) *counter = 0;
  ws_[tid] = watt_s[tid]; ws_[tid+256] = watt_s[tid+256];
  wd_[tid] = watt_d[tid]; wd_[tid+256] = watt_d[tid+256];
  __syncthreads();
  int r = tid>>2, q = tid&3;
  int grow = blk*64 + r;
  const float* xr = x + (size_t)grow*ND + q*128;
  float ssq = 0.f, as = 0.f, ad = 0.f;
  #pragma unroll
  for (int c8 = 0; c8 < 16; ++c8) {
    float4 v0 = *(const float4*)&xr[c8*8];
    float4 v1 = *(const float4*)&xr[c8*8+4];
    float vv[8] = {v0.x,v0.y,v0.z,v0.w,v1.x,v1.y,v1.z,v1.w};
    #pragma unroll
    for (int j = 0; j < 8; ++j) {
      int c = q*128 + c8*8 + j;
      ssq = fmaf(vv[j], vv[j], ssq);
      as  = fmaf(vv[j], ws_[c], as);
      ad  = fmaf(vv[j], wd_[c], ad);
    }
  }
  ssq += __shfl_xor(ssq, 1, 64); ssq += __shfl_xor(ssq, 2, 64);
  as  += __shfl_xor(as, 1, 64);  as  += __shfl_xor(as, 2, 64);
  ad  += __shfl_xor(ad, 1, 64);  ad  += __shfl_xor(ad, 2, 64);
  float rn = 1.0f / fmaxf(sqrtf(ssq), 1e-12f);
  if (q == 0) { rnorm[grow] = rn; a_src[grow] = as; a_dst[grow] = ad; }
  int trow = grow & (NS-1), b = grow >> 10;
  int m = (trow>>4)&7, rr = trow&15;
  size_t tilebase = ((size_t)(b*8 + (trow>>7)))*65536;
  #pragma unroll
  for (int c8 = 0; c8 < 16; ++c8) {
    int col = q*128 + c8*8;
    int k0c = col>>6, cc = col&63, kb = cc>>5, g = (cc>>3)&3;
    int id = kb*512 + m*64 + g*16 + rr;
    size_t off = tilebase + (size_t)k0c*8192 + id*8;
    float4 v0 = *(const float4*)&xr[c8*8];
    float4 v1 = *(const float4*)&xr[c8*8+4];
    float vv[8] = {v0.x,v0.y,v0.z,v0.w,v1.x,v1.y,v1.z,v1.w};
    union { unsigned short us[8]; uint4 u; } ph, pl;
    #pragma unroll
    for (int j = 0; j < 8; ++j) {
      float y = vv[j]*rn;
      unsigned yb = __float_as_uint(y);
      float hf = __uint_as_float(yb & 0xFFFF0000u);
      float lf = y - hf;                       // exact
      ph.us[j] = (unsigned short)(yb >> 16);
      pl.us[j] = (unsigned short)(__float_as_uint(lf) >> 16);
    }
    *(uint4*)&yhi[off] = ph.u;
    *(uint4*)&ylo[off] = pl.u;
  }
}

// ---------------- K4: sim via split-bf16 MFMA (3-term), unchanged from proven r7 ----------------
__global__ __launch_bounds__(256) void k_sim_mfma(const __hip_bfloat16* __restrict__ yhi,
                                                  const __hip_bfloat16* __restrict__ ylo,
                                                  uint8_t* __restrict__ Mmask,
                                                  unsigned int* __restrict__ list,
                                                  int* __restrict__ counter) {
  int bid = blockIdx.x;
  int swz = (bid & 7)*72 + (bid >> 3);      // bijective: 576 = 8*72
  int b = swz / 36, p = swz - b*36;
  int ti = 0;
  while ((ti+1)*(ti+2)/2 <= p) ++ti;
  int tj = p - ti*(ti+1)/2;                 // tj <= ti
  __shared__ __hip_bfloat16 Ahi[8192], Alo[8192], Bhi[8192], Blo[8192];
  int tid = threadIdx.x, wid = tid>>6, lane = tid&63;
  int wm = (wid>>1)*64, wn = (wid&1)*64;
  bool diag = (ti == tj);
  const __hip_bfloat16* Bh = diag ? Ahi : Bhi;
  const __hip_bfloat16* Bl = diag ? Alo : Blo;
  f32x4 acc[4][4] = {};
  for (int k0c = 0; k0c < 8; ++k0c) {
    __syncthreads();
    size_t abase = ((size_t)((b*8+ti)*8 + k0c))*8192 + wid*2048 + lane*8;
    size_t bbase = ((size_t)((b*8+tj)*8 + k0c))*8192 + wid*2048 + lane*8;
    int lb = wid*2048;
    #pragma unroll
    for (int i = 0; i < 4; ++i) {
      GLOAD_LDS16(yhi + abase + i*512, &Ahi[lb + i*512]);
      GLOAD_LDS16(ylo + abase + i*512, &Alo[lb + i*512]);
    }
    if (!diag) {
      #pragma unroll
      for (int i = 0; i < 4; ++i) {
        GLOAD_LDS16(yhi + bbase + i*512, &Bhi[lb + i*512]);
        GLOAD_LDS16(ylo + bbase + i*512, &Blo[lb + i*512]);
      }
    }
    __syncthreads();
    #pragma unroll
    for (int kb = 0; kb < 2; ++kb) {
      bf16x8 ah[4], al[4], bh[4], bl[4];
      #pragma unroll
      for (int q = 0; q < 4; ++q) {
        int aoff = ((kb*8 + (wm>>4) + q)*64 + lane)*8;
        ah[q] = *(const bf16x8*)&Ahi[aoff];
        al[q] = *(const bf16x8*)&Alo[aoff];
        int boff = ((kb*8 + (wn>>4) + q)*64 + lane)*8;
        bh[q] = *(const bf16x8*)&Bh[boff];
        bl[q] = *(const bf16x8*)&Bl[boff];
      }
      #pragma unroll
      for (int mi = 0; mi < 4; ++mi)
        #pragma unroll
        for (int ni = 0; ni < 4; ++ni) {
          acc[mi][ni] = __builtin_amdgcn_mfma_f32_16x16x32_bf16(ah[mi], bh[ni], acc[mi][ni], 0,0,0);
          acc[mi][ni] = __builtin_amdgcn_mfma_f32_16x16x32_bf16(ah[mi], bl[ni], acc[mi][ni], 0,0,0);
          acc[mi][ni] = __builtin_amdgcn_mfma_f32_16x16x32_bf16(al[mi], bh[ni], acc[mi][ni], 0,0,0);
        }
    }
  }
  int rbase = (lane>>4)*4, colL = lane&15;
  #pragma unroll
  for (int mi = 0; mi < 4; ++mi) {
    #pragma unroll
    for (int r2 = 0; r2 < 4; ++r2) {
      int t_g = ti*128 + wm + mi*16 + rbase + r2;
      int git = b*NS + t_g;
      uint8_t* Mrow = Mmask + (size_t)git*NS;
      #pragma unroll
      for (int ni = 0; ni < 4; ++ni) {
        int s_g = tj*128 + wn + ni*16 + colL;
        if (s_g > t_g) continue;
        float sim = acc[mi][ni][r2];
        bool edge = (s_g == t_g) || (sim > 0.9f);
        if (s_g < t_g && fabsf(sim - 0.9f) <= SIM_BAND) {
          int idx = atomicAdd(counter, 1);
          if (idx < LIST_CAP) list[idx] = ((unsigned)b<<20) | ((unsigned)t_g<<10) | (unsigned)s_g;
        }
        Mrow[s_g] = edge ? 1 : 0;
      }
    }
  }
}

// ---------------- K5: exact f32 recheck of borderline pairs -> fix mask bytes ----------------
__global__ __launch_bounds__(256) void k_recheck(const float* __restrict__ x,
                                                 const float* __restrict__ rnorm,
                                                 uint8_t* __restrict__ Mmask,
                                                 const unsigned int* __restrict__ list,
                                                 const int* __restrict__ counter) {
  int n = *counter;
  if (n > LIST_CAP) n = LIST_CAP;
  int gid = blockIdx.x*256 + threadIdx.x;
  for (int i = gid; i < n; i += 256*256) {
    unsigned v = list[i];
    int b = v>>20, t = (v>>10)&1023, s = v&1023;
    const float* xt = x + ((size_t)(b*NS + t))*ND;
    const float* xs = x + ((size_t)(b*NS + s))*ND;
    float4 a4 = {0.f,0.f,0.f,0.f};
    for (int k = 0; k < ND; k += 4) {
      float4 av = *(const float4*)&xt[k];
      float4 bv = *(const float4*)&xs[k];
      a4.x = fmaf(av.x,bv.x,a4.x); a4.y = fmaf(av.y,bv.y,a4.y);
      a4.z = fmaf(av.z,bv.z,a4.z); a4.w = fmaf(av.w,bv.w,a4.w);
    }
    float dot = (a4.x+a4.y)+(a4.z+a4.w);
    float sim = dot * rnorm[b*NS+t] * rnorm[b*NS+s];
    Mmask[((size_t)(b*NS+t))*NS + s] = (sim > 0.9f) ? 1 : 0;
  }
}

// ---------------- K6: htf (frag-order, 16-tile k-panes) = (W^T @ y) * ||x|| ----------------
// grid 512 1D, XCD-swizzled. htf tile index: (mt*NB + b)*16 + k0c, k0c in 0..15 (i-dim 1024/64).
__global__ __launch_bounds__(256) void k_gemm_ht(const __hip_bfloat16* __restrict__ Wf,
                                                 const __hip_bfloat16* __restrict__ yhi,
                                                 const __hip_bfloat16* __restrict__ ylo,
                                                 const float* __restrict__ rnorm,
                                                 __hip_bfloat16* __restrict__ htf) {
  int bid = blockIdx.x;
  int swz = (bid&7)*64 + (bid>>3);          // bijective: 512 = 8*64
  int mt = swz&3, it = swz>>2;              // it in [0,128)
  int b = it>>3, tblk = it&7;
  __shared__ __hip_bfloat16 Aw[8192], Bhi[8192], Blo[8192];
  int tid = threadIdx.x, wid = tid>>6, lane = tid&63;
  int wm = (wid>>1)*64, wn = (wid&1)*64;
  f32x4 acc[4][4] = {};
  for (int k0c = 0; k0c < 8; ++k0c) {
    __syncthreads();
    size_t abase = ((size_t)(mt*8 + k0c))*8192 + wid*2048 + lane*8;
    size_t bbase = ((size_t)((b*8+tblk)*8 + k0c))*8192 + wid*2048 + lane*8;
    int lb = wid*2048;
    #pragma unroll
    for (int i = 0; i < 4; ++i) {
      GLOAD_LDS16(Wf  + abase + i*512, &Aw [lb + i*512]);
      GLOAD_LDS16(yhi + bbase + i*512, &Bhi[lb + i*512]);
      GLOAD_LDS16(ylo + bbase + i*512, &Blo[lb + i*512]);
    }
    __syncthreads();
    #pragma unroll
    for (int kb = 0; kb < 2; ++kb) {
      bf16x8 a[4], bh[4], bl[4];
      #pragma unroll
      for (int q = 0; q < 4; ++q) {
        a [q] = *(const bf16x8*)&Aw [((kb*8 + (wm>>4) + q)*64 + lane)*8];
        bh[q] = *(const bf16x8*)&Bhi[((kb*8 + (wn>>4) + q)*64 + lane)*8];
        bl[q] = *(const bf16x8*)&Blo[((kb*8 + (wn>>4) + q)*64 + lane)*8];
      }
      #pragma unroll
      for (int mi = 0; mi < 4; ++mi)
        #pragma unroll
        for (int ni = 0; ni < 4; ++ni) {
          acc[mi][ni] = __builtin_amdgcn_mfma_f32_16x16x32_bf16(a[mi], bh[ni], acc[mi][ni], 0,0,0);
          acc[mi][ni] = __builtin_amdgcn_mfma_f32_16x16x32_bf16(a[mi], bl[ni], acc[mi][ni], 0,0,0);
        }
    }
  }
  // epilogue: scale column i by ||x_i||, store into frag-order htf (pane stride 16 tiles)
  int rbase = (lane>>4)*4, colL = lane&15;
  int n0 = it*128;
  #pragma unroll
  for (int ni = 0; ni < 4; ++ni) {
    int gn = n0 + wn + ni*16 + colL;        // global i
    float xn = 1.0f / rnorm[gn];
    int icol = gn & 1023;
    int k0c = icol>>6, cc = icol&63, kb = cc>>5, g = (cc>>3)&3, j = icol&7;
    size_t colbase = ((size_t)((mt*NB + b)*16 + k0c))*8192 + (size_t)(kb*512 + g*16)*8 + j;
    #pragma unroll
    for (int mi = 0; mi < 4; ++mi)
      #pragma unroll
      for (int r2 = 0; r2 < 4; ++r2) {
        int o_local = wm + mi*16 + rbase + r2;
        int m = o_local>>4, r = o_local&15;
        htf[colbase + (size_t)(m*64 + r)*8] = __float2bfloat16(acc[mi][ni][r2] * xn);
      }
  }
}

// ---------------- K7: masked softmax, wave per row -> P frag-order (16-tile s-panes) ----------------
__global__ __launch_bounds__(256) void k_softmax(const uint8_t* __restrict__ Mmask,
                                                 const float* __restrict__ a_src,
                                                 const float* __restrict__ a_dst,
                                                 __hip_bfloat16* __restrict__ Pf) {
  int wid = threadIdx.x>>6, lane = threadIdx.x&63;
  int rowid = blockIdx.x*4 + wid;           // grid 4096
  int t = rowid & (NS-1), b = rowid >> 10;
  int n = t + 1;
  const float* as = a_src + b*NS;
  float adv = a_dst[rowid];
  const uint8_t* Mrow = Mmask + (size_t)rowid*NS;
  int s0 = lane*16;
  uint4 mb = *(const uint4*)(Mrow + s0);
  unsigned mw[4] = {mb.x, mb.y, mb.z, mb.w};
  float4 a0 = *(const float4*)&as[s0];
  float4 a1 = *(const float4*)&as[s0+4];
  float4 a2 = *(const float4*)&as[s0+8];
  float4 a3 = *(const float4*)&as[s0+12];
  float va[16] = {a0.x,a0.y,a0.z,a0.w, a1.x,a1.y,a1.z,a1.w,
                  a2.x,a2.y,a2.z,a2.w, a3.x,a3.y,a3.z,a3.w};
  float pr[16];
  float lm = -INFINITY;
  #pragma unroll
  for (int k = 0; k < 16; ++k) {
    int s = s0 + k;
    bool on = (s < n) && (((mw[k>>2] >> ((k&3)*8)) & 255u) != 0u);
    float vv = adv + va[k];
    float v = (vv > 0.f) ? vv : 0.2f*vv;
    pr[k] = on ? v : -INFINITY;
    lm = fmaxf(lm, pr[k]);
  }
  #pragma unroll
  for (int off = 32; off > 0; off >>= 1) lm = fmaxf(lm, __shfl_xor(lm, off, 64));
  float ls = 0.f;
  #pragma unroll
  for (int k = 0; k < 16; ++k) { pr[k] = __expf(pr[k] - lm); ls += pr[k]; }
  #pragma unroll
  for (int off = 32; off > 0; off >>= 1) ls += __shfl_xor(ls, off, 64);
  float inv = 1.0f / ls;
  int end = ((t >> 7) + 1) << 7;
  if (s0 < end) {
    int m = (t>>4)&7, r = t&15;
    size_t tbase = ((size_t)(b*8 + (t>>7)))*131072;   // pane = 16 tiles x 8192
    #pragma unroll
    for (int h = 0; h < 2; ++h) {
      int icol = s0 + h*8;
      int k0c = icol>>6, cc = icol&63, kb = cc>>5, g = (cc>>3)&3;
      size_t off = tbase + (size_t)k0c*8192 + (size_t)(kb*512 + m*64 + g*16 + r)*8;
      union { unsigned short us[8]; uint4 u; } pk;
      #pragma unroll
      for (int j = 0; j < 8; ++j) pk.us[j] = f2bs(pr[h*8+j]*inv);
      *(uint4*)&Pf[off] = pk.u;
    }
  }
}

// ---------------- K8: out = relu(P @ h + bias), frag-order operands (16-tile panes) ----------------
__global__ __launch_bounds__(256) void k_pv(const __hip_bfloat16* __restrict__ Pf,
                                            const __hip_bfloat16* __restrict__ htf,
                                            const float* __restrict__ bias,
                                            float* __restrict__ out) {
  int bid = blockIdx.x;
  int swz = (bid&7)*64 + (bid>>3);          // bijective: 512 = 8*64
  int b = swz>>5, rem = swz&31, mt = rem>>2, nt = rem&3;
  __shared__ __hip_bfloat16 At[8192], Bt[8192];
  int tid = threadIdx.x, wid = tid>>6, lane = tid&63;
  int wm = (wid>>1)*64, wn = (wid&1)*64;
  f32x4 acc[4][4] = {};
  int nk = 2*(mt+1);
  for (int k0c = 0; k0c < nk; ++k0c) {
    __syncthreads();
    size_t abase = ((size_t)((b*8 + mt)*16 + k0c))*8192 + wid*2048 + lane*8;
    size_t bbase = ((size_t)((nt*NB + b)*16 + k0c))*8192 + wid*2048 + lane*8;
    int lb = wid*2048;
    #pragma unroll
    for (int i = 0; i < 4; ++i) {
      GLOAD_LDS16(Pf  + abase + i*512, &At[lb + i*512]);
      GLOAD_LDS16(htf + bbase + i*512, &Bt[lb + i*512]);
    }
    __syncthreads();
    #pragma unroll
    for (int kb = 0; kb < 2; ++kb) {
      bf16x8 a[4], bb[4];
      #pragma unroll
      for (int q = 0; q < 4; ++q) {
        a [q] = *(const bf16x8*)&At[((kb*8 + (wm>>4) + q)*64 + lane)*8];
        bb[q] = *(const bf16x8*)&Bt[((kb*8 + (wn>>4) + q)*64 + lane)*8];
      }
      #pragma unroll
      for (int mi = 0; mi < 4; ++mi)
        #pragma unroll
        for (int ni = 0; ni < 4; ++ni)
          acc[mi][ni] = __builtin_amdgcn_mfma_f32_16x16x32_bf16(a[mi], bb[ni], acc[mi][ni], 0,0,0);
    }
  }
  int m0 = mt*128, n0 = nt*128;
  int rbase = (lane>>4)*4, col = lane&15;
  #pragma unroll
  for (int mi = 0; mi < 4; ++mi)
    #pragma unroll
    for (int ni = 0; ni < 4; ++ni) {
      int gm = m0 + wm + mi*16 + rbase;
      int gn = n0 + wn + ni*16 + col;
      float bv = bias[gn];
      #pragma unroll
      for (int r2 = 0; r2 < 4; ++r2)
        out[((size_t)b*NS + gm + r2)*NO + gn] = fmaxf(acc[mi][ni][r2] + bv, 0.0f);
    }
}

extern "C" void kernel_launch(void* const* d_in, const int* in_sizes, int n_in,
                              void* d_out, int out_size, void* d_ws, size_t ws_size,
                              hipStream_t stream) {
  (void)in_sizes; (void)n_in; (void)out_size; (void)ws_size;
  const float* x       = (const float*)d_in[0];
  const float* W       = (const float*)d_in[1];
  const float* att_src = (const float*)d_in[2];
  const float* att_dst = (const float*)d_in[3];
  const float* bias    = (const float*)d_in[4];
  float* out = (float*)d_out;

  char* ws = (char*)d_ws;
  // Proven 67.8MB map. Lifetimes:
  __hip_bfloat16* yhi   = (__hip_bfloat16*)(ws + 0);           // 16 MB [prep_y..gemm_ht]
  __hip_bfloat16* ylo   = (__hip_bfloat16*)(ws + 16777216);    // 16 MB [prep_y..gemm_ht]
  __hip_bfloat16* Pf    = (__hip_bfloat16*)(ws + 0);           // 32 MB [softmax..pv] (aliases yhi/ylo; softmax runs after gemm_ht)
  int*            cnt   = (int*)          (ws + 33554432);     // 16 B  [prep_y..recheck]
  unsigned int*   list  = (unsigned int*) (ws + 33554448);     //  4 MB [sim..recheck]
  __hip_bfloat16* htf   = (__hip_bfloat16*)(ws + 33554432);    // 16 MB [gemm_ht..pv] (aliases cnt/list)
  uint8_t*        Mmask = (uint8_t*)      (ws + 50331648);     // 16 MB [sim..softmax]
  float*          watt_s= (float*)        (ws + 50331648);     //  2 KB [prep_watt..prep_y] (inside Mmask, dead before sim)
  float*          watt_d= (float*)        (ws + 50333696);     //  2 KB
  __hip_bfloat16* Wf    = (__hip_bfloat16*)(ws + 67108864);    // 512 KB [prep_wfrag..gemm_ht]
  float*          rnorm = (float*)        (ws + 67633152);     // 64 KB [prep_y..gemm_ht]
  float*          a_src = (float*)        (ws + 67698688);     // 64 KB [prep_y..softmax]
  float*          a_dst = (float*)        (ws + 67764224);     // 64 KB [prep_y..softmax]

  k_prep_wfrag<<<dim3(4,8),  dim3(256),   0, stream>>>(W, Wf);
  k_prep_watt <<<dim3(2),    dim3(256),   0, stream>>>(W, att_src, att_dst, watt_s, watt_d);
  k_prep_y    <<<dim3(256),  dim3(256),   0, stream>>>(x, yhi, ylo, rnorm, a_src, a_dst, watt_s, watt_d, cnt);
  k_sim_mfma  <<<dim3(576),  dim3(256),   0, stream>>>(yhi, ylo, Mmask, list, cnt);
  k_recheck   <<<dim3(256),  dim3(256),   0, stream>>>(x, rnorm, Mmask, list, cnt);
  k_gemm_ht   <<<dim3(512),  dim3(256),   0, stream>>>(Wf, yhi, ylo, rnorm, htf);
  k_softmax   <<<dim3(4096), dim3(256),   0, stream>>>(Mmask, a_src, a_dst, Pf);
  k_pv        <<<dim3(512),  dim3(256),   0, stream>>>(Pf, htf, bias, out);
}